// Round 15
// baseline (268.703 us; speedup 1.0000x reference)
//
#include <hip/hip_runtime.h>
#include <math.h>

typedef __attribute__((ext_vector_type(8))) short short8;
typedef __attribute__((ext_vector_type(4))) short bh4;
typedef __attribute__((ext_vector_type(4))) float f32x4;
typedef __attribute__((ext_vector_type(2))) unsigned uint2v;
typedef __attribute__((ext_vector_type(4))) unsigned uint4v;

#define MFMA16(A,B,C) __builtin_amdgcn_mfma_f32_16x16x32_bf16(A,B,C,0,0,0)

#if __has_builtin(__builtin_amdgcn_mfma_f32_16x16x16bf16_1k)
#define MFMA16x16(A,B,C) __builtin_amdgcn_mfma_f32_16x16x16bf16_1k(A,B,C,0,0,0)
#else
__device__ __forceinline__ f32x4 mfma16x16_asm(bh4 a, bh4 b, f32x4 c){
    asm volatile("v_mfma_f32_16x16x16_bf16 %0, %1, %2, %0" : "+v"(c) : "v"(a), "v"(b));
    return c;
}
#define MFMA16x16(A,B,C) mfma16x16_asm(A,B,C)
#endif

__device__ __forceinline__ unsigned short f2b(float f){
    unsigned u = __builtin_bit_cast(unsigned, f);
    return (unsigned short)((u + 0x7fffu + ((u>>16)&1u)) >> 16);
}
__device__ __forceinline__ unsigned pk2(float a, float b){
    return (unsigned)f2b(a) | ((unsigned)f2b(b) << 16);
}
__device__ __forceinline__ unsigned pk2rn(float a, float b){
    unsigned ua = __builtin_bit_cast(unsigned, a) + 0x8000u;
    unsigned ub = __builtin_bit_cast(unsigned, b) + 0x8000u;
    return (ua >> 16) | (ub & 0xffff0000u);
}

// ws layout (bytes):
//  R    @ 0         : 16*784 rows x 1024B bf16  (q | kv-packed | xm/xa staging)
//  pws  @ 12845056  : [16*28*4][1792] f32 conv partials (12.8MB)
//  srwb @ 25690112  : bf16 srw [64][4096]
//  Wtm  @ 26214400  : bf16 (k1w|v1w)^T [128][256]
//  Wta  @ 26279936  : bf16 (k2w|v2w)^T [128][256]
//  QWt  @ 26345472  : bf16 qw^T [64][64]
//  z    @ 12845056  : f32 (aliases pws; alive after k2 only)

// ---------------- ktw: one-time weight convert/transpose ----------------
__global__ __launch_bounds__(256) void ktw(const float* __restrict__ srw,
    const float* __restrict__ qw, const float* __restrict__ k1w,
    const float* __restrict__ v1w, const float* __restrict__ k2w,
    const float* __restrict__ v2w, char* __restrict__ srwb,
    char* __restrict__ Wtm, char* __restrict__ Wta, char* __restrict__ QWt)
{
    int blk = blockIdx.x, t = threadIdx.x;
    if (blk < 128){
        int base = blk*2048 + t*8;
        float4 a = *(const float4*)(srw + base);
        float4 b = *(const float4*)(srw + base + 4);
        uint4 u = { pk2(a.x,a.y), pk2(a.z,a.w), pk2(b.x,b.y), pk2(b.z,b.w) };
        *(uint4*)(srwb + (size_t)base*2) = u;
    } else if (blk < 136){
        __shared__ float T[256*33];
        int idx = blk - 128, fi = idx >> 1, half = idx & 1;
        const float* src = (fi==0) ? k1w : (fi==1) ? v1w : (fi==2) ? k2w : v2w;
        char* dst = ((fi < 2) ? Wtm : Wta) + (size_t)((fi & 1)*64 + half*32) * 512;
        for (int li = t; li < 8192; li += 256){
            int c = li >> 5, o = li & 31;
            T[c*33 + o] = src[c*64 + half*32 + o];
        }
        __syncthreads();
        for (int lo = t; lo < 1024; lo += 256){
            int o = lo >> 5, c8 = lo & 31;
            float v[8];
            #pragma unroll
            for (int k = 0; k < 8; ++k) v[k] = T[(c8*8 + k)*33 + o];
            uint4 u = { pk2(v[0],v[1]), pk2(v[2],v[3]), pk2(v[4],v[5]), pk2(v[6],v[7]) };
            *(uint4*)(dst + o*512 + c8*16) = u;
        }
    } else {
        __shared__ float T[64*65];
        for (int li = t; li < 4096; li += 256)
            T[(li >> 6)*65 + (li & 63)] = qw[li];
        __syncthreads();
        for (int lo = t; lo < 512; lo += 256){
            int o = lo >> 3, i8 = lo & 7;
            float v[8];
            #pragma unroll
            for (int k = 0; k < 8; ++k) v[k] = T[(i8*8 + k)*65 + o];
            uint4 u = { pk2(v[0],v[1]), pk2(v[2],v[3]), pk2(v[4],v[5]), pk2(v[6],v[7]) };
            *(uint4*)(QWt + o*128 + i8*16) = u;
        }
    }
}

// ---------------- k1 v10: minimal-footprint asm streamer (max waves/CU) ----------
// grid (b,hs,cg4) = 1792 blocks, 256 threads (4 waves = 4 o-frags, N-split).
// LDS = 7.4KB (packed pool only); launch_bounds(256,6) caps VGPR ~84 so up to
// 6 blocks/CU = 24 waves/CU stay resident. asm loads (un-sinkable), 2-step
// pipeline = 10 loads in flight/wave; counted vmcnt; no main-loop barriers.
__global__ __launch_bounds__(256, 6) void k1(const float* __restrict__ x,
    const char* __restrict__ srwb, char* __restrict__ R, float* __restrict__ pws)
{
    __shared__ unsigned pmpa[28*66];
    int blk = blockIdx.x;
    int b = blk / 112, r5 = blk % 112, hs = r5 >> 2, cg4 = r5 & 3;
    int t = threadIdx.x;
    int w = t >> 6, l = t & 63, lr = l & 15, lg = l >> 4;
    int cpar = lg >> 1, r0 = (lg & 1) * 2;
    f32x4 acc0 = {0.f,0.f,0.f,0.f}, acc1 = {0.f,0.f,0.f,0.f};
    const float* xc = x + (size_t)(b*256 + cg4*64)*12544 + (size_t)(hs*4 + r0)*112;
    const char* Brow = srwb + (size_t)(w*16 + lr)*8192 + cg4*2048 + lg*16;
    int p0 = lr, p1 = min(16 + lr, 27);

    f32x4 A0,A1,A2,A3; uint4v Ba;
    f32x4 C0,C1,C2,C3; uint4v Bc;

#define ISSUE(Xa,Xb,Xc,Xd,Bv,KS) do{ \
    const float* _s = xc + (size_t)((KS)*2 + cpar)*12544; \
    const char*  _bp = Brow + (KS)*64; \
    asm volatile("global_load_dwordx4 %0, %1, off" : "=&v"(Xa) : "v"(_s + p0*4)); \
    asm volatile("global_load_dwordx4 %0, %1, off" : "=&v"(Xb) : "v"(_s + 112 + p0*4)); \
    asm volatile("global_load_dwordx4 %0, %1, off" : "=&v"(Xc) : "v"(_s + p1*4)); \
    asm volatile("global_load_dwordx4 %0, %1, off" : "=&v"(Xd) : "v"(_s + 112 + p1*4)); \
    asm volatile("global_load_dwordx4 %0, %1, off" : "=&v"(Bv) : "v"(_bp)); }while(0)

#define WAITN(N) do{ asm volatile("s_waitcnt vmcnt(" #N ")" ::: "memory"); \
                     __builtin_amdgcn_sched_barrier(0); }while(0)

#define COMP(Xa,Xb,Xc,Xd,Bv,KS) do{ \
    if (w == 0){ \
        float mx0 = fmaxf(fmaxf(fmaxf(Xa[0],Xa[1]),fmaxf(Xa[2],Xa[3])), \
                          fmaxf(fmaxf(Xb[0],Xb[1]),fmaxf(Xb[2],Xb[3]))); \
        float sm0 = (Xa[0]+Xa[1])+(Xa[2]+Xa[3])+(Xb[0]+Xb[1])+(Xb[2]+Xb[3]); \
        float mx1 = fmaxf(fmaxf(fmaxf(Xc[0],Xc[1]),fmaxf(Xc[2],Xc[3])), \
                          fmaxf(fmaxf(Xd[0],Xd[1]),fmaxf(Xd[2],Xd[3]))); \
        float sm1 = (Xc[0]+Xc[1])+(Xc[2]+Xc[3])+(Xd[0]+Xd[1])+(Xd[2]+Xd[3]); \
        mx0 = fmaxf(mx0, __shfl_xor(mx0, 16, 64)); \
        sm0 = sm0 + __shfl_xor(sm0, 16, 64); \
        mx1 = fmaxf(mx1, __shfl_xor(mx1, 16, 64)); \
        sm1 = sm1 + __shfl_xor(sm1, 16, 64); \
        if ((lg & 1) == 0){ \
            int c = (KS)*2 + cpar; \
            pmpa[p0*66 + c] = pk2(mx0, sm0 * (1.f/16.f)); \
            if (lr < 12) pmpa[p1*66 + c] = pk2(mx1, sm1 * (1.f/16.f)); \
        } \
    } \
    short8 af0 = __builtin_bit_cast(short8, \
        (uint4v){ pk2(Xa[0],Xa[1]), pk2(Xa[2],Xa[3]), pk2(Xb[0],Xb[1]), pk2(Xb[2],Xb[3]) }); \
    short8 af1 = __builtin_bit_cast(short8, \
        (uint4v){ pk2(Xc[0],Xc[1]), pk2(Xc[2],Xc[3]), pk2(Xd[0],Xd[1]), pk2(Xd[2],Xd[3]) }); \
    short8 bf = __builtin_bit_cast(short8, Bv); \
    acc0 = MFMA16(af0, bf, acc0); \
    acc1 = MFMA16(af1, bf, acc1); }while(0)

    ISSUE(A0,A1,A2,A3,Ba, 0);
    ISSUE(C0,C1,C2,C3,Bc, 1);
    #pragma unroll 1
    for (int it = 0; it < 15; ++it){
        int s2 = it*2;
        WAITN(5); COMP(A0,A1,A2,A3,Ba, s2);   ISSUE(A0,A1,A2,A3,Ba, s2+2);
        WAITN(5); COMP(C0,C1,C2,C3,Bc, s2+1); ISSUE(C0,C1,C2,C3,Bc, s2+3);
    }
    WAITN(5); COMP(A0,A1,A2,A3,Ba, 30);
    WAITN(0); COMP(C0,C1,C2,C3,Bc, 31);

#undef ISSUE
#undef WAITN
#undef COMP

    size_t rowB = (size_t)b*784 + hs*28;
    float* pp = pws + (size_t)((b*28 + hs)*4 + cg4)*1792;
    #pragma unroll
    for (int rg = 0; rg < 4; ++rg){
        int m0 = lg*4 + rg, m1 = 16 + lg*4 + rg;
        pp[m0*64 + w*16 + lr] = acc0[rg];
        if (m1 < 28) pp[m1*64 + w*16 + lr] = acc1[rg];
    }
    __syncthreads();
    if (t < 224){
        int m = t >> 3, sub = t & 7;
        unsigned u[8];
        #pragma unroll
        for (int k = 0; k < 8; ++k) u[k] = pmpa[m*66 + sub*8 + k];
        uint4 um = { (u[0]&0xffffu)|(u[1]<<16), (u[2]&0xffffu)|(u[3]<<16),
                     (u[4]&0xffffu)|(u[5]<<16), (u[6]&0xffffu)|(u[7]<<16) };
        uint4 ua = { (u[0]>>16)|(u[1]&0xffff0000u), (u[2]>>16)|(u[3]&0xffff0000u),
                     (u[4]>>16)|(u[5]&0xffff0000u), (u[6]>>16)|(u[7]&0xffff0000u) };
        *(uint4*)(R + (rowB + m)*1024 + cg4*128 + sub*16)       = um;
        *(uint4*)(R + (rowB + m)*1024 + 512 + cg4*128 + sub*16) = ua;
    }
}

// ---------------- k2: 4-partial sum + LN + qGEMM + pool GEMMs ----------------
__global__ __launch_bounds__(512) void k2(const float* __restrict__ pws_,
    const float* __restrict__ srb, const float* __restrict__ lng,
    const float* __restrict__ lnb, const char* __restrict__ Wtm,
    const char* __restrict__ Wta, const char* __restrict__ QWt,
    char* __restrict__ R)
{
    __shared__ __align__(16) char PM[16384];
    __shared__ __align__(16) char PA[16384];
    __shared__ float Db[32*64];
    __shared__ __align__(16) char QN[4096];
    int blk = blockIdx.x, b = blk/28, hs = blk%28;
    int t = threadIdx.x, w = t>>6, l = t&63, lr = l&15, lg = l>>4;
    size_t rowB = (size_t)b*784 + hs*28;
    const char* Rb = R + rowB*1024;
    for (int li = t; li < 896; li += 512){
        int m = li >> 5, c16 = li & 31;
        uint4 vm = *(const uint4*)(Rb + (size_t)m*1024 + c16*16);
        uint4 va = *(const uint4*)(Rb + (size_t)m*1024 + 512 + c16*16);
        int dst = m*512 + ((c16*16) ^ ((m&7)<<4));
        *(uint4*)(PM + dst) = vm;
        *(uint4*)(PA + dst) = va;
    }
    const float* p0 = pws_ + (size_t)(b*28 + hs)*4*1792;
    for (int e = t; e < 1792; e += 512)
        Db[e] = ((p0[e] + p0[1792+e]) + (p0[3584+e] + p0[5376+e])) + srb[e & 63];
    __syncthreads();
    float g = lng[l], be = lnb[l];
    #pragma unroll
    for (int i = 0; i < 4; ++i){
        int m = w + i*8;
        float v = Db[m*64 + l];
        float s = v, ss = v*v;
        #pragma unroll
        for (int off = 1; off < 64; off <<= 1){
            s  += __shfl_xor(s,  off, 64);
            ss += __shfl_xor(ss, off, 64);
        }
        float mu = s * (1.f/64.f);
        float var = ss * (1.f/64.f) - mu*mu;
        float qn = (v - mu) * rsqrtf(var + 1e-5f) * g + be;
        *(unsigned short*)(QN + m*128 + ((l*2) ^ ((m&7)<<4))) = f2b(qn);
    }
    __syncthreads();
    int fam = w >> 2, ofp = w & 3;
    const char* PMA = fam ? PA : PM;
    const char* Wt  = fam ? Wta : Wtm;
    f32x4 a00={0.f,0.f,0.f,0.f}, a01=a00, a10=a00, a11=a00;
    int swzr = (lr & 7) << 4;
    #pragma unroll
    for (int ks = 0; ks < 8; ++ks){
        int kb = ks*64 + lg*16;
        short8 x0 = *(const short8*)(PMA + lr*512 + (kb ^ swzr));
        short8 x1 = *(const short8*)(PMA + (16+lr)*512 + (kb ^ swzr));
        short8 b0 = *(const short8*)(Wt + (size_t)(ofp*32 + lr)*512 + kb);
        short8 b1 = *(const short8*)(Wt + (size_t)(ofp*32 + 16 + lr)*512 + kb);
        a00 = MFMA16(x0, b0, a00); a01 = MFMA16(x0, b1, a01);
        a10 = MFMA16(x1, b0, a10); a11 = MFMA16(x1, b1, a11);
    }
    f32x4 q0={0.f,0.f,0.f,0.f}, q1=q0;
    if (w < 4){
        #pragma unroll
        for (int ks = 0; ks < 2; ++ks){
            int kb = ks*64 + lg*16;
            short8 xa_ = *(const short8*)(QN + lr*128 + (kb ^ swzr));
            short8 xb_ = *(const short8*)(QN + (16+lr)*128 + (kb ^ swzr));
            short8 bq  = *(const short8*)(QWt + (size_t)(w*16 + lr)*128 + kb);
            q0 = MFMA16(xa_, bq, q0);
            q1 = MFMA16(xb_, bq, q1);
        }
    }
    #pragma unroll
    for (int j = 0; j < 2; ++j){
        int o128 = ofp*32 + j*16 + lr;
        int o = o128 & 63, hh = o >> 3, dd = o & 7, mat = fam*2 + (o128 >> 6);
        int byteoff = 128 + hh*64 + mat*16 + dd*2;
        f32x4 am  = j ? a01 : a00;
        f32x4 am1 = j ? a11 : a10;
        #pragma unroll
        for (int rg = 0; rg < 4; ++rg){
            int m0 = lg*4 + rg, m1 = 16 + lg*4 + rg;
            *(unsigned short*)(R + (rowB + m0)*1024 + byteoff) = f2b(am[rg]);
            if (m1 < 28)
                *(unsigned short*)(R + (rowB + m1)*1024 + byteoff) = f2b(am1[rg]);
        }
    }
    if (w < 4){
        int o = w*16 + lr;
        #pragma unroll
        for (int rg = 0; rg < 4; ++rg){
            int m0 = lg*4 + rg, m1 = 16 + lg*4 + rg;
            *(unsigned short*)(R + (rowB + m0)*1024 + o*2) = f2b(q0[rg]);
            if (m1 < 28)
                *(unsigned short*)(R + (rowB + m1)*1024 + o*2) = f2b(q1[rg]);
        }
    }
}

// ---------------- kattn: MFMA dual attention (swapped-operand, hd=8 pad 16) ----------------
__global__ __launch_bounds__(256) void kattn(const char* __restrict__ R, float* __restrict__ z)
{
    __shared__ __align__(16) char QT [6144];
    __shared__ __align__(16) char K1b[5376];
    __shared__ __align__(16) char K2b[5376];
    __shared__ __align__(16) char VT1[3840];
    __shared__ __align__(16) char VT2[3840];
    int blk = blockIdx.x;
    int bh = blk / 7, nseg = blk % 7;
    int b = bh >> 3, h = bh & 7;
    int t = threadIdx.x, w = t >> 6, l = t & 63;
    int col = l & 15, g = l >> 4;

    for (int i = t; i < 384; i += 256) ((uint4*)QT)[i] = uint4{0,0,0,0};
    for (int i = t; i < 112; i += 256){
        *(uint4*)(K1b + i*48 + 16) = uint4{0,0,0,0};
        *(uint4*)(K2b + i*48 + 16) = uint4{0,0,0,0};
    }
    for (int i = t; i < 120; i += 256){
        *(uint4*)(VT1 + 1920 + i*16) = uint4{0,0,0,0};
        *(uint4*)(VT2 + 1920 + i*16) = uint4{0,0,0,0};
    }
    __syncthreads();
    if (t < 112){
        uint4 qv = *(const uint4*)(R + ((size_t)b*784 + nseg*112 + t)*1024 + h*16);
        *(uint2*)(QT + t*48)     = uint2{qv.x, qv.y};
        *(uint2*)(QT + t*48 + 8) = uint2{qv.z, qv.w};
    }
    __syncthreads();

    bh4 qf[2];
    #pragma unroll
    for (int nf = 0; nf < 2; ++nf)
        qf[nf] = *(const bh4*)(QT + (w*28 + nf*16 + col)*48 + g*8);

    f32x4 o1[2] = {{0,0,0,0},{0,0,0,0}}, o2[2] = {{0,0,0,0},{0,0,0,0}};
    float d1[2] = {0.f,0.f}, d2[2] = {0.f,0.f};
    const float C2 = 0.51004244f;

    for (int mt = 0; mt < 7; ++mt){
        __syncthreads();
        for (int li = t; li < 448; li += 256){
            int m = li >> 2, part = li & 3;
            uint4 v = *(const uint4*)(R + ((size_t)b*784 + mt*112 + m)*1024 + 128 + h*64 + part*16);
            if ((part & 1) == 0){
                char* Kb = (part == 0) ? K1b : K2b;
                *(uint2*)(Kb + m*48)     = uint2{v.x, v.y};
                *(uint2*)(Kb + m*48 + 8) = uint2{v.z, v.w};
            } else {
                char* Vb = (part == 1) ? VT1 : VT2;
                unsigned arr[4] = {v.x, v.y, v.z, v.w};
                #pragma unroll
                for (int d = 0; d < 4; ++d){
                    *(unsigned short*)(Vb + (d*2)*240   + m*2) = (unsigned short)(arr[d] & 0xffffu);
                    *(unsigned short*)(Vb + (d*2+1)*240 + m*2) = (unsigned short)(arr[d] >> 16);
                }
            }
        }
        __syncthreads();
        #pragma unroll
        for (int mc = 0; mc < 7; ++mc){
            bh4 ka = *(const bh4*)(K1b + (mc*16 + col)*48 + g*8);
            bh4 kb = *(const bh4*)(K2b + (mc*16 + col)*48 + g*8);
            bh4 va = *(const bh4*)(VT1 + col*240 + mc*32 + g*8);
            bh4 vb = *(const bh4*)(VT2 + col*240 + mc*32 + g*8);
            #pragma unroll
            for (int nf = 0; nf < 2; ++nf){
                f32x4 zr = {0.f,0.f,0.f,0.f};
                f32x4 s1 = MFMA16x16(ka, qf[nf], zr);
                float p0 = exp2f(s1[0]*C2), p1 = exp2f(s1[1]*C2);
                float p2 = exp2f(s1[2]*C2), p3 = exp2f(s1[3]*C2);
                d1[nf] += (p0+p1)+(p2+p3);
                bh4 pf1 = __builtin_bit_cast(bh4, (uint2v){pk2rn(p0,p1), pk2rn(p2,p3)});
                o1[nf] = MFMA16x16(va, pf1, o1[nf]);
                f32x4 s2 = MFMA16x16(kb, qf[nf], zr);
                float r0 = exp2f(s2[0]*C2), r1 = exp2f(s2[1]*C2);
                float r2 = exp2f(s2[2]*C2), r3 = exp2f(s2[3]*C2);
                d2[nf] += (r0+r1)+(r2+r3);
                bh4 pf2 = __builtin_bit_cast(bh4, (uint2v){pk2rn(r0,r1), pk2rn(r2,r3)});
                o2[nf] = MFMA16x16(vb, pf2, o2[nf]);
            }
        }
    }
    #pragma unroll
    for (int nf = 0; nf < 2; ++nf){
        d1[nf] += __shfl_xor(d1[nf], 16, 64); d1[nf] += __shfl_xor(d1[nf], 32, 64);
        d2[nf] += __shfl_xor(d2[nf], 16, 64); d2[nf] += __shfl_xor(d2[nf], 32, 64);
    }
    if (g < 2){
        #pragma unroll
        for (int nf = 0; nf < 2; ++nf){
            if (nf == 1 && col >= 12) continue;
            int n = nseg*112 + w*28 + nf*16 + col;
            float ra = 1.f / d1[nf], rb = 1.f / d2[nf];
            float4 ov;
            ov.x = o1[nf][0]*ra + o2[nf][0]*rb;
            ov.y = o1[nf][1]*ra + o2[nf][1]*rb;
            ov.z = o1[nf][2]*ra + o2[nf][2]*rb;
            ov.w = o1[nf][3]*ra + o2[nf][3]*rb;
            *(float4*)(z + ((size_t)b*784 + n)*64 + h*8 + g*4) = ov;
        }
    }
}

// ---------------- kpu: proj (64->256) + bilinear upsample (float4 stores) ----------------
__global__ __launch_bounds__(256) void kpu(const float* __restrict__ z,
    const float* __restrict__ pw, const float* __restrict__ pb,
    float* __restrict__ out)
{
    __shared__ float plane[8*784];
    __shared__ float wsl[64*8];
    __shared__ int   ti0[112];
    __shared__ float twv[112];
    int blk = blockIdx.x;
    int b = blk >> 5, cg = blk & 31;
    int t = threadIdx.x;
    if (t < 128){
        #pragma unroll
        for (int q = 0; q < 4; ++q){
            int idx = t*4 + q; int o = idx >> 3, j = idx & 7;
            wsl[o*8 + j] = pw[o*256 + cg*8 + j];
        }
    }
    if (t < 112){
        float s = (float)t * (27.f/111.f);
        int i0 = (int)s; if (i0 > 27) i0 = 27;
        ti0[t] = i0; twv[t] = s - (float)i0;
    }
    __syncthreads();
    {
        int nh = t >> 1, jh = (t & 1) * 4;
        float bias0 = pb[cg*8 + jh], bias1 = pb[cg*8 + jh + 1];
        float bias2 = pb[cg*8 + jh + 2], bias3 = pb[cg*8 + jh + 3];
        for (int n = nh; n < 784; n += 128){
            const float* zr = z + ((size_t)b*784 + n)*64;
            float a0 = bias0, a1 = bias1, a2 = bias2, a3 = bias3;
            #pragma unroll
            for (int o4 = 0; o4 < 16; ++o4){
                float4 zv = *(const float4*)(zr + o4*4);
                const float* wr = wsl + (o4*4)*8 + jh;
                a0 = fmaf(zv.x, wr[0],  a0); a1 = fmaf(zv.x, wr[1],  a1);
                a2 = fmaf(zv.x, wr[2],  a2); a3 = fmaf(zv.x, wr[3],  a3);
                a0 = fmaf(zv.y, wr[8],  a0); a1 = fmaf(zv.y, wr[9],  a1);
                a2 = fmaf(zv.y, wr[10], a2); a3 = fmaf(zv.y, wr[11], a3);
                a0 = fmaf(zv.z, wr[16], a0); a1 = fmaf(zv.z, wr[17], a1);
                a2 = fmaf(zv.z, wr[18], a2); a3 = fmaf(zv.z, wr[19], a3);
                a0 = fmaf(zv.w, wr[24], a0); a1 = fmaf(zv.w, wr[25], a1);
                a2 = fmaf(zv.w, wr[26], a2); a3 = fmaf(zv.w, wr[27], a3);
            }
            plane[(jh+0)*784 + n] = a0;
            plane[(jh+1)*784 + n] = a1;
            plane[(jh+2)*784 + n] = a2;
            plane[(jh+3)*784 + n] = a3;
        }
    }
    __syncthreads();
    float* ob = out + ((size_t)b*256 + cg*8)*12544;
    for (int i4 = t; i4 < 3136; i4 += 256){
        int y = i4 / 28, xq = (i4 % 28) * 4;
        int y0 = ti0[y], y1 = min(y0+1, 27);
        float wy = twv[y];
        int x0q[4], x1q[4]; float wxq[4];
        #pragma unroll
        for (int qi = 0; qi < 4; ++qi){
            int xx = xq + qi;
            x0q[qi] = ti0[xx]; x1q[qi] = min(x0q[qi]+1, 27); wxq[qi] = twv[xx];
        }
        int base = y*112 + xq;
        #pragma unroll
        for (int j = 0; j < 8; ++j){
            const float* r0p = plane + j*784 + y0*28;
            const float* r1p = plane + j*784 + y1*28;
            float4 ov;
            #pragma unroll
            for (int qi = 0; qi < 4; ++qi){
                float a  = r0p[x0q[qi]] + (r1p[x0q[qi]] - r0p[x0q[qi]])*wy;
                float bb = r0p[x1q[qi]] + (r1p[x1q[qi]] - r0p[x1q[qi]])*wy;
                float v = a + (bb - a)*wxq[qi];
                if (qi == 0) ov.x = v; else if (qi == 1) ov.y = v;
                else if (qi == 2) ov.z = v; else ov.w = v;
            }
            *(float4*)(ob + (size_t)j*12544 + base) = ov;
        }
    }
}

extern "C" void kernel_launch(void* const* d_in, const int* in_sizes, int n_in,
                              void* d_out, int out_size, void* d_ws, size_t ws_size,
                              hipStream_t stream) {
    const float* x   = (const float*)d_in[0];
    const float* srw = (const float*)d_in[1];
    const float* srb = (const float*)d_in[2];
    const float* lng = (const float*)d_in[3];
    const float* lnb = (const float*)d_in[4];
    const float* qw  = (const float*)d_in[5];
    const float* k1w = (const float*)d_in[6];
    const float* v1w = (const float*)d_in[7];
    const float* k2w = (const float*)d_in[8];
    const float* v2w = (const float*)d_in[9];
    const float* pw  = (const float*)d_in[10];
    const float* pb  = (const float*)d_in[11];

    char*  Rws  = (char*)d_ws;
    float* pws  = (float*)(Rws + 12845056);
    char*  srwb = Rws + 25690112;
    char*  Wtm  = Rws + 26214400;
    char*  Wta  = Rws + 26279936;
    char*  QWt  = Rws + 26345472;
    float* z    = (float*)(Rws + 12845056);   // aliases pws (dead after k2)
    float* out  = (float*)d_out;

    ktw  <<<137,  256, 0, stream>>>(srw, qw, k1w, v1w, k2w, v2w, srwb, Wtm, Wta, QWt);
    k1   <<<1792, 256, 0, stream>>>(x, srwb, Rws, pws);
    k2   <<<448,  512, 0, stream>>>(pws, srb, lng, lnb, Wtm, Wta, QWt, Rws);
    kattn<<<896,  256, 0, stream>>>(Rws, z);
    kpu  <<<512,  256, 0, stream>>>(z, pw, pb, out);
}

// Round 16
// 232.728 us; speedup vs baseline: 1.1546x; 1.1546x over previous
//
#include <hip/hip_runtime.h>
#include <math.h>

typedef __attribute__((ext_vector_type(8))) short short8;
typedef __attribute__((ext_vector_type(4))) short bh4;
typedef __attribute__((ext_vector_type(4))) float f32x4;
typedef __attribute__((ext_vector_type(2))) unsigned uint2v;
typedef __attribute__((ext_vector_type(4))) unsigned uint4v;

#define MFMA16(A,B,C) __builtin_amdgcn_mfma_f32_16x16x32_bf16(A,B,C,0,0,0)

#if __has_builtin(__builtin_amdgcn_mfma_f32_16x16x16bf16_1k)
#define MFMA16x16(A,B,C) __builtin_amdgcn_mfma_f32_16x16x16bf16_1k(A,B,C,0,0,0)
#else
__device__ __forceinline__ f32x4 mfma16x16_asm(bh4 a, bh4 b, f32x4 c){
    asm volatile("v_mfma_f32_16x16x16_bf16 %0, %1, %2, %0" : "+v"(c) : "v"(a), "v"(b));
    return c;
}
#define MFMA16x16(A,B,C) mfma16x16_asm(A,B,C)
#endif

__device__ __forceinline__ unsigned short f2b(float f){
    unsigned u = __builtin_bit_cast(unsigned, f);
    return (unsigned short)((u + 0x7fffu + ((u>>16)&1u)) >> 16);
}
__device__ __forceinline__ unsigned pk2(float a, float b){
    return (unsigned)f2b(a) | ((unsigned)f2b(b) << 16);
}
__device__ __forceinline__ unsigned pk2rn(float a, float b){
    unsigned ua = __builtin_bit_cast(unsigned, a) + 0x8000u;
    unsigned ub = __builtin_bit_cast(unsigned, b) + 0x8000u;
    return (ua >> 16) | (ub & 0xffff0000u);
}
__device__ __forceinline__ void gl_lds16(const void* g, void* l){
    __builtin_amdgcn_global_load_lds(
        (const __attribute__((address_space(1))) void*)g,
        (__attribute__((address_space(3))) void*)l, 16, 0, 0);
}

// ws layout (bytes):
//  R    @ 0         : 16*784 rows x 1024B bf16  (q | kv-packed | xm/xa staging)
//  pws  @ 12845056  : [16*28*4][1792] f32 conv partials
//  srwb @ 25690112  : bf16 srw [64][4096]
//  Wtm  @ 26214400  : bf16 (k1w|v1w)^T [128][256]
//  Wta  @ 26279936  : bf16 (k2w|v2w)^T [128][256]
//  QWt  @ 26345472  : bf16 qw^T [64][64]
//  z    @ 12845056  : f32 (aliases pws; alive after k2 only)

// ---------------- ktw: one-time weight convert/transpose ----------------
__global__ __launch_bounds__(256) void ktw(const float* __restrict__ srw,
    const float* __restrict__ qw, const float* __restrict__ k1w,
    const float* __restrict__ v1w, const float* __restrict__ k2w,
    const float* __restrict__ v2w, char* __restrict__ srwb,
    char* __restrict__ Wtm, char* __restrict__ Wta, char* __restrict__ QWt)
{
    int blk = blockIdx.x, t = threadIdx.x;
    if (blk < 128){
        int base = blk*2048 + t*8;
        float4 a = *(const float4*)(srw + base);
        float4 b = *(const float4*)(srw + base + 4);
        uint4 u = { pk2(a.x,a.y), pk2(a.z,a.w), pk2(b.x,b.y), pk2(b.z,b.w) };
        *(uint4*)(srwb + (size_t)base*2) = u;
    } else if (blk < 136){
        __shared__ float T[256*33];
        int idx = blk - 128, fi = idx >> 1, half = idx & 1;
        const float* src = (fi==0) ? k1w : (fi==1) ? v1w : (fi==2) ? k2w : v2w;
        char* dst = ((fi < 2) ? Wtm : Wta) + (size_t)((fi & 1)*64 + half*32) * 512;
        for (int li = t; li < 8192; li += 256){
            int c = li >> 5, o = li & 31;
            T[c*33 + o] = src[c*64 + half*32 + o];
        }
        __syncthreads();
        for (int lo = t; lo < 1024; lo += 256){
            int o = lo >> 5, c8 = lo & 31;
            float v[8];
            #pragma unroll
            for (int k = 0; k < 8; ++k) v[k] = T[(c8*8 + k)*33 + o];
            uint4 u = { pk2(v[0],v[1]), pk2(v[2],v[3]), pk2(v[4],v[5]), pk2(v[6],v[7]) };
            *(uint4*)(dst + o*512 + c8*16) = u;
        }
    } else {
        __shared__ float T[64*65];
        for (int li = t; li < 4096; li += 256)
            T[(li >> 6)*65 + (li & 63)] = qw[li];
        __syncthreads();
        for (int lo = t; lo < 512; lo += 256){
            int o = lo >> 3, i8 = lo & 7;
            float v[8];
            #pragma unroll
            for (int k = 0; k < 8; ++k) v[k] = T[(i8*8 + k)*65 + o];
            uint4 u = { pk2(v[0],v[1]), pk2(v[2],v[3]), pk2(v[4],v[5]), pk2(v[6],v[7]) };
            *(uint4*)(QWt + o*128 + i8*16) = u;
        }
    }
}

// ---------------- k1: conv + pool, 3-deep DMA pipeline (r10-verified best) ----------------
// grid (b,hs,cg4) = 1792 blocks, 256 threads. 8 stages x 8 channels.
// 3 LDS buffers; B-frags prefetched 3 stages ahead in named regs so all waits
// are counted vmcnt (never drain-0 until the tail). x read exactly once.
__global__ __launch_bounds__(256) void k1(const float* __restrict__ x,
    const char* __restrict__ srwb, char* __restrict__ R, float* __restrict__ pws)
{
    __shared__ __align__(16) char Xb0[14336];
    __shared__ __align__(16) char Xb1[14336];
    __shared__ __align__(16) char Xb2[14336];
    __shared__ unsigned pmpa[28*66];
    int blk = blockIdx.x;
    int b = blk / 112, r5 = blk % 112, hs = r5 >> 2, cg4 = r5 & 3;
    int t = threadIdx.x;
    int w = t >> 6, l = t & 63, lr = l & 15, lg = l >> 4;
    int p0 = lr, p1m = min(16 + lr, 27);
    int nIss = (w < 3) ? 4 : 2;
    int jbase = (w < 3) ? w*4 : 12;

    size_t gchunk[4]; int ldso[4];
    #pragma unroll
    for (int q = 0; q < 4; ++q){
        int byte_in = (jbase + q)*1024 + l*16;
        int c = byte_in / 1792, rem = byte_in - c*1792;
        gchunk[q] = (size_t)c*50176 + rem;
        ldso[q] = (jbase + q)*1024;
    }
    const char* xstage = (const char*)x
        + ((size_t)(b*256 + cg4*64)*12544 + (size_t)hs*448)*4;
    const char* bRow = srwb + (size_t)(w*16 + lr)*8192 + cg4*2048 + lg*16;
    int pl_p = t >> 3, pl_c = t & 7;

    f32x4 acc0 = {0.f,0.f,0.f,0.f}, acc1 = {0.f,0.f,0.f,0.f};
    short8 Q00,Q01,Q02,Q03, Q10,Q11,Q12,Q13, Q20,Q21,Q22,Q23;

#define BPRE(B0,B1,B2,B3,S) do{ \
    B0 = *(const short8*)(bRow + (S)*256);      \
    B1 = *(const short8*)(bRow + (S)*256 + 64); \
    B2 = *(const short8*)(bRow + (S)*256 + 128);\
    B3 = *(const short8*)(bRow + (S)*256 + 192); }while(0)

#define STAGE(XB,S) do{ \
    const char* _gb = xstage + (size_t)(S)*401408; \
    _Pragma("unroll") for (int q = 0; q < 4; ++q){ \
        if (q < nIss) gl_lds16(_gb + gchunk[q], XB + ldso[q]); } }while(0)

#define WAIT16 do{ if (w < 3) asm volatile("s_waitcnt vmcnt(16)" ::: "memory"); \
                   else       asm volatile("s_waitcnt vmcnt(12)" ::: "memory"); \
                   __builtin_amdgcn_sched_barrier(0); }while(0)
#define WAIT8  do{ if (w < 3) asm volatile("s_waitcnt vmcnt(8)" ::: "memory"); \
                   else       asm volatile("s_waitcnt vmcnt(6)" ::: "memory"); \
                   __builtin_amdgcn_sched_barrier(0); }while(0)
#define WAIT0  do{ asm volatile("s_waitcnt vmcnt(0)" ::: "memory"); \
                   __builtin_amdgcn_sched_barrier(0); }while(0)
#define BAR    do{ __builtin_amdgcn_s_barrier(); __builtin_amdgcn_sched_barrier(0); }while(0)

#define COMP(XB,B0,B1,B2,B3,S) do{ \
    if (t < 224){ \
        const char* cb = XB + pl_c*1792 + pl_p*16; \
        f32x4 r0 = *(const f32x4*)(cb);        f32x4 r1 = *(const f32x4*)(cb + 448); \
        f32x4 r2 = *(const f32x4*)(cb + 896);  f32x4 r3 = *(const f32x4*)(cb + 1344); \
        float mx = fmaxf(fmaxf(fmaxf(r0[0],r0[1]),fmaxf(r0[2],r0[3])), \
                         fmaxf(fmaxf(r1[0],r1[1]),fmaxf(r1[2],r1[3]))); \
        mx = fmaxf(mx, fmaxf(fmaxf(fmaxf(r2[0],r2[1]),fmaxf(r2[2],r2[3])), \
                             fmaxf(fmaxf(r3[0],r3[1]),fmaxf(r3[2],r3[3])))); \
        float sm = ((r0[0]+r0[1])+(r0[2]+r0[3])) + ((r1[0]+r1[1])+(r1[2]+r1[3])) \
                 + ((r2[0]+r2[1])+(r2[2]+r2[3])) + ((r3[0]+r3[1])+(r3[2]+r3[3])); \
        pmpa[pl_p*66 + (S)*8 + pl_c] = pk2(mx, sm * (1.f/16.f)); \
    } \
    _Pragma("unroll") for (int ks = 0; ks < 4; ++ks){ \
        const char* abase = XB + (ks*2 + (lg>>1))*1792 + (lg&1)*896; \
        f32x4 lo0 = *(const f32x4*)(abase + p0*16); \
        f32x4 hi0 = *(const f32x4*)(abase + 448 + p0*16); \
        f32x4 lo1 = *(const f32x4*)(abase + p1m*16); \
        f32x4 hi1 = *(const f32x4*)(abase + 448 + p1m*16); \
        short8 af0 = __builtin_bit_cast(short8, \
            (uint4v){ pk2(lo0[0],lo0[1]), pk2(lo0[2],lo0[3]), pk2(hi0[0],hi0[1]), pk2(hi0[2],hi0[3]) }); \
        short8 af1 = __builtin_bit_cast(short8, \
            (uint4v){ pk2(lo1[0],lo1[1]), pk2(lo1[2],lo1[3]), pk2(hi1[0],hi1[1]), pk2(hi1[2],hi1[3]) }); \
        short8 bq = (ks==0)?B0:(ks==1)?B1:(ks==2)?B2:B3; \
        acc0 = MFMA16(af0, bq, acc0); \
        acc1 = MFMA16(af1, bq, acc1); } }while(0)

    // prologue: 3 stages in flight (issue order: B_s before S_s, s ascending)
    BPRE(Q00,Q01,Q02,Q03, 0); STAGE(Xb0, 0);
    BPRE(Q10,Q11,Q12,Q13, 1); STAGE(Xb1, 1);
    BPRE(Q20,Q21,Q22,Q23, 2); STAGE(Xb2, 2);

    WAIT16; BAR; COMP(Xb0, Q00,Q01,Q02,Q03, 0); BAR;
    BPRE(Q00,Q01,Q02,Q03, 3); STAGE(Xb0, 3);
    WAIT16; BAR; COMP(Xb1, Q10,Q11,Q12,Q13, 1); BAR;
    BPRE(Q10,Q11,Q12,Q13, 4); STAGE(Xb1, 4);
    WAIT16; BAR; COMP(Xb2, Q20,Q21,Q22,Q23, 2); BAR;
    BPRE(Q20,Q21,Q22,Q23, 5); STAGE(Xb2, 5);
    WAIT16; BAR; COMP(Xb0, Q00,Q01,Q02,Q03, 3); BAR;
    BPRE(Q00,Q01,Q02,Q03, 6); STAGE(Xb0, 6);
    WAIT16; BAR; COMP(Xb1, Q10,Q11,Q12,Q13, 4); BAR;
    BPRE(Q10,Q11,Q12,Q13, 7); STAGE(Xb1, 7);
    WAIT16; BAR; COMP(Xb2, Q20,Q21,Q22,Q23, 5); BAR;
    WAIT8;  BAR; COMP(Xb0, Q00,Q01,Q02,Q03, 6); BAR;
    WAIT0;  BAR; COMP(Xb1, Q10,Q11,Q12,Q13, 7);

#undef BPRE
#undef STAGE
#undef WAIT16
#undef WAIT8
#undef WAIT0
#undef BAR
#undef COMP

    size_t rowB = (size_t)b*784 + hs*28;
    float* pp = pws + (size_t)((b*28 + hs)*4 + cg4)*1792;
    #pragma unroll
    for (int rg = 0; rg < 4; ++rg){
        int m0 = lg*4 + rg, m1 = 16 + lg*4 + rg;
        pp[m0*64 + w*16 + lr] = acc0[rg];
        if (m1 < 28) pp[m1*64 + w*16 + lr] = acc1[rg];
    }
    __syncthreads();
    if (t < 224){
        int m = t >> 3, sub = t & 7;
        unsigned u[8];
        #pragma unroll
        for (int k = 0; k < 8; ++k) u[k] = pmpa[m*66 + sub*8 + k];
        uint4 um = { (u[0]&0xffffu)|(u[1]<<16), (u[2]&0xffffu)|(u[3]<<16),
                     (u[4]&0xffffu)|(u[5]<<16), (u[6]&0xffffu)|(u[7]<<16) };
        uint4 ua = { (u[0]>>16)|(u[1]&0xffff0000u), (u[2]>>16)|(u[3]&0xffff0000u),
                     (u[4]>>16)|(u[5]&0xffff0000u), (u[6]>>16)|(u[7]&0xffff0000u) };
        *(uint4*)(R + (rowB + m)*1024 + cg4*128 + sub*16)       = um;
        *(uint4*)(R + (rowB + m)*1024 + 512 + cg4*128 + sub*16) = ua;
    }
}

// ---------------- k2: 4-partial sum + LN + qGEMM + pool GEMMs ----------------
__global__ __launch_bounds__(512) void k2(const float* __restrict__ pws_,
    const float* __restrict__ srb, const float* __restrict__ lng,
    const float* __restrict__ lnb, const char* __restrict__ Wtm,
    const char* __restrict__ Wta, const char* __restrict__ QWt,
    char* __restrict__ R)
{
    __shared__ __align__(16) char PM[16384];
    __shared__ __align__(16) char PA[16384];
    __shared__ float Db[32*64];
    __shared__ __align__(16) char QN[4096];
    int blk = blockIdx.x, b = blk/28, hs = blk%28;
    int t = threadIdx.x, w = t>>6, l = t&63, lr = l&15, lg = l>>4;
    size_t rowB = (size_t)b*784 + hs*28;
    const char* Rb = R + rowB*1024;
    for (int li = t; li < 896; li += 512){
        int m = li >> 5, c16 = li & 31;
        uint4 vm = *(const uint4*)(Rb + (size_t)m*1024 + c16*16);
        uint4 va = *(const uint4*)(Rb + (size_t)m*1024 + 512 + c16*16);
        int dst = m*512 + ((c16*16) ^ ((m&7)<<4));
        *(uint4*)(PM + dst) = vm;
        *(uint4*)(PA + dst) = va;
    }
    const float* p0 = pws_ + (size_t)(b*28 + hs)*4*1792;
    for (int e = t; e < 1792; e += 512)
        Db[e] = ((p0[e] + p0[1792+e]) + (p0[3584+e] + p0[5376+e])) + srb[e & 63];
    __syncthreads();
    float g = lng[l], be = lnb[l];
    #pragma unroll
    for (int i = 0; i < 4; ++i){
        int m = w + i*8;
        float v = Db[m*64 + l];
        float s = v, ss = v*v;
        #pragma unroll
        for (int off = 1; off < 64; off <<= 1){
            s  += __shfl_xor(s,  off, 64);
            ss += __shfl_xor(ss, off, 64);
        }
        float mu = s * (1.f/64.f);
        float var = ss * (1.f/64.f) - mu*mu;
        float qn = (v - mu) * rsqrtf(var + 1e-5f) * g + be;
        *(unsigned short*)(QN + m*128 + ((l*2) ^ ((m&7)<<4))) = f2b(qn);
    }
    __syncthreads();
    int fam = w >> 2, ofp = w & 3;
    const char* PMA = fam ? PA : PM;
    const char* Wt  = fam ? Wta : Wtm;
    f32x4 a00={0.f,0.f,0.f,0.f}, a01=a00, a10=a00, a11=a00;
    int swzr = (lr & 7) << 4;
    #pragma unroll
    for (int ks = 0; ks < 8; ++ks){
        int kb = ks*64 + lg*16;
        short8 x0 = *(const short8*)(PMA + lr*512 + (kb ^ swzr));
        short8 x1 = *(const short8*)(PMA + (16+lr)*512 + (kb ^ swzr));
        short8 b0 = *(const short8*)(Wt + (size_t)(ofp*32 + lr)*512 + kb);
        short8 b1 = *(const short8*)(Wt + (size_t)(ofp*32 + 16 + lr)*512 + kb);
        a00 = MFMA16(x0, b0, a00); a01 = MFMA16(x0, b1, a01);
        a10 = MFMA16(x1, b0, a10); a11 = MFMA16(x1, b1, a11);
    }
    f32x4 q0={0.f,0.f,0.f,0.f}, q1=q0;
    if (w < 4){
        #pragma unroll
        for (int ks = 0; ks < 2; ++ks){
            int kb = ks*64 + lg*16;
            short8 xa_ = *(const short8*)(QN + lr*128 + (kb ^ swzr));
            short8 xb_ = *(const short8*)(QN + (16+lr)*128 + (kb ^ swzr));
            short8 bq  = *(const short8*)(QWt + (size_t)(w*16 + lr)*128 + kb);
            q0 = MFMA16(xa_, bq, q0);
            q1 = MFMA16(xb_, bq, q1);
        }
    }
    #pragma unroll
    for (int j = 0; j < 2; ++j){
        int o128 = ofp*32 + j*16 + lr;
        int o = o128 & 63, hh = o >> 3, dd = o & 7, mat = fam*2 + (o128 >> 6);
        int byteoff = 128 + hh*64 + mat*16 + dd*2;
        f32x4 am  = j ? a01 : a00;
        f32x4 am1 = j ? a11 : a10;
        #pragma unroll
        for (int rg = 0; rg < 4; ++rg){
            int m0 = lg*4 + rg, m1 = 16 + lg*4 + rg;
            *(unsigned short*)(R + (rowB + m0)*1024 + byteoff) = f2b(am[rg]);
            if (m1 < 28)
                *(unsigned short*)(R + (rowB + m1)*1024 + byteoff) = f2b(am1[rg]);
        }
    }
    if (w < 4){
        int o = w*16 + lr;
        #pragma unroll
        for (int rg = 0; rg < 4; ++rg){
            int m0 = lg*4 + rg, m1 = 16 + lg*4 + rg;
            *(unsigned short*)(R + (rowB + m0)*1024 + o*2) = f2b(q0[rg]);
            if (m1 < 28)
                *(unsigned short*)(R + (rowB + m1)*1024 + o*2) = f2b(q1[rg]);
        }
    }
}

// ---------------- kattn: MFMA dual attention (swapped-operand, hd=8 pad 16) ----------------
__global__ __launch_bounds__(256) void kattn(const char* __restrict__ R, float* __restrict__ z)
{
    __shared__ __align__(16) char QT [6144];
    __shared__ __align__(16) char K1b[5376];
    __shared__ __align__(16) char K2b[5376];
    __shared__ __align__(16) char VT1[3840];
    __shared__ __align__(16) char VT2[3840];
    int blk = blockIdx.x;
    int bh = blk / 7, nseg = blk % 7;
    int b = bh >> 3, h = bh & 7;
    int t = threadIdx.x, w = t >> 6, l = t & 63;
    int col = l & 15, g = l >> 4;

    for (int i = t; i < 384; i += 256) ((uint4*)QT)[i] = uint4{0,0,0,0};
    for (int i = t; i < 112; i += 256){
        *(uint4*)(K1b + i*48 + 16) = uint4{0,0,0,0};
        *(uint4*)(K2b + i*48 + 16) = uint4{0,0,0,0};
    }
    for (int i = t; i < 120; i += 256){
        *(uint4*)(VT1 + 1920 + i*16) = uint4{0,0,0,0};
        *(uint4*)(VT2 + 1920 + i*16) = uint4{0,0,0,0};
    }
    __syncthreads();
    if (t < 112){
        uint4 qv = *(const uint4*)(R + ((size_t)b*784 + nseg*112 + t)*1024 + h*16);
        *(uint2*)(QT + t*48)     = uint2{qv.x, qv.y};
        *(uint2*)(QT + t*48 + 8) = uint2{qv.z, qv.w};
    }
    __syncthreads();

    bh4 qf[2];
    #pragma unroll
    for (int nf = 0; nf < 2; ++nf)
        qf[nf] = *(const bh4*)(QT + (w*28 + nf*16 + col)*48 + g*8);

    f32x4 o1[2] = {{0,0,0,0},{0,0,0,0}}, o2[2] = {{0,0,0,0},{0,0,0,0}};
    float d1[2] = {0.f,0.f}, d2[2] = {0.f,0.f};
    const float C2 = 0.51004244f;

    for (int mt = 0; mt < 7; ++mt){
        __syncthreads();
        for (int li = t; li < 448; li += 256){
            int m = li >> 2, part = li & 3;
            uint4 v = *(const uint4*)(R + ((size_t)b*784 + mt*112 + m)*1024 + 128 + h*64 + part*16);
            if ((part & 1) == 0){
                char* Kb = (part == 0) ? K1b : K2b;
                *(uint2*)(Kb + m*48)     = uint2{v.x, v.y};
                *(uint2*)(Kb + m*48 + 8) = uint2{v.z, v.w};
            } else {
                char* Vb = (part == 1) ? VT1 : VT2;
                unsigned arr[4] = {v.x, v.y, v.z, v.w};
                #pragma unroll
                for (int d = 0; d < 4; ++d){
                    *(unsigned short*)(Vb + (d*2)*240   + m*2) = (unsigned short)(arr[d] & 0xffffu);
                    *(unsigned short*)(Vb + (d*2+1)*240 + m*2) = (unsigned short)(arr[d] >> 16);
                }
            }
        }
        __syncthreads();
        #pragma unroll
        for (int mc = 0; mc < 7; ++mc){
            bh4 ka = *(const bh4*)(K1b + (mc*16 + col)*48 + g*8);
            bh4 kb = *(const bh4*)(K2b + (mc*16 + col)*48 + g*8);
            bh4 va = *(const bh4*)(VT1 + col*240 + mc*32 + g*8);
            bh4 vb = *(const bh4*)(VT2 + col*240 + mc*32 + g*8);
            #pragma unroll
            for (int nf = 0; nf < 2; ++nf){
                f32x4 zr = {0.f,0.f,0.f,0.f};
                f32x4 s1 = MFMA16x16(ka, qf[nf], zr);
                float p0 = exp2f(s1[0]*C2), p1 = exp2f(s1[1]*C2);
                float p2 = exp2f(s1[2]*C2), p3 = exp2f(s1[3]*C2);
                d1[nf] += (p0+p1)+(p2+p3);
                bh4 pf1 = __builtin_bit_cast(bh4, (uint2v){pk2rn(p0,p1), pk2rn(p2,p3)});
                o1[nf] = MFMA16x16(va, pf1, o1[nf]);
                f32x4 s2 = MFMA16x16(kb, qf[nf], zr);
                float r0 = exp2f(s2[0]*C2), r1 = exp2f(s2[1]*C2);
                float r2 = exp2f(s2[2]*C2), r3 = exp2f(s2[3]*C2);
                d2[nf] += (r0+r1)+(r2+r3);
                bh4 pf2 = __builtin_bit_cast(bh4, (uint2v){pk2rn(r0,r1), pk2rn(r2,r3)});
                o2[nf] = MFMA16x16(vb, pf2, o2[nf]);
            }
        }
    }
    #pragma unroll
    for (int nf = 0; nf < 2; ++nf){
        d1[nf] += __shfl_xor(d1[nf], 16, 64); d1[nf] += __shfl_xor(d1[nf], 32, 64);
        d2[nf] += __shfl_xor(d2[nf], 16, 64); d2[nf] += __shfl_xor(d2[nf], 32, 64);
    }
    if (g < 2){
        #pragma unroll
        for (int nf = 0; nf < 2; ++nf){
            if (nf == 1 && col >= 12) continue;
            int n = nseg*112 + w*28 + nf*16 + col;
            float ra = 1.f / d1[nf], rb = 1.f / d2[nf];
            float4 ov;
            ov.x = o1[nf][0]*ra + o2[nf][0]*rb;
            ov.y = o1[nf][1]*ra + o2[nf][1]*rb;
            ov.z = o1[nf][2]*ra + o2[nf][2]*rb;
            ov.w = o1[nf][3]*ra + o2[nf][3]*rb;
            *(float4*)(z + ((size_t)b*784 + n)*64 + h*8 + g*4) = ov;
        }
    }
}

// ---------------- kpu: proj (64->256) + bilinear upsample (float4 stores) ----------------
__global__ __launch_bounds__(256) void kpu(const float* __restrict__ z,
    const float* __restrict__ pw, const float* __restrict__ pb,
    float* __restrict__ out)
{
    __shared__ float plane[8*784];
    __shared__ float wsl[64*8];
    __shared__ int   ti0[112];
    __shared__ float twv[112];
    int blk = blockIdx.x;
    int b = blk >> 5, cg = blk & 31;
    int t = threadIdx.x;
    if (t < 128){
        #pragma unroll
        for (int q = 0; q < 4; ++q){
            int idx = t*4 + q; int o = idx >> 3, j = idx & 7;
            wsl[o*8 + j] = pw[o*256 + cg*8 + j];
        }
    }
    if (t < 112){
        float s = (float)t * (27.f/111.f);
        int i0 = (int)s; if (i0 > 27) i0 = 27;
        ti0[t] = i0; twv[t] = s - (float)i0;
    }
    __syncthreads();
    {
        int nh = t >> 1, jh = (t & 1) * 4;
        float bias0 = pb[cg*8 + jh], bias1 = pb[cg*8 + jh + 1];
        float bias2 = pb[cg*8 + jh + 2], bias3 = pb[cg*8 + jh + 3];
        for (int n = nh; n < 784; n += 128){
            const float* zr = z + ((size_t)b*784 + n)*64;
            float a0 = bias0, a1 = bias1, a2 = bias2, a3 = bias3;
            #pragma unroll
            for (int o4 = 0; o4 < 16; ++o4){
                float4 zv = *(const float4*)(zr + o4*4);
                const float* wr = wsl + (o4*4)*8 + jh;
                a0 = fmaf(zv.x, wr[0],  a0); a1 = fmaf(zv.x, wr[1],  a1);
                a2 = fmaf(zv.x, wr[2],  a2); a3 = fmaf(zv.x, wr[3],  a3);
                a0 = fmaf(zv.y, wr[8],  a0); a1 = fmaf(zv.y, wr[9],  a1);
                a2 = fmaf(zv.y, wr[10], a2); a3 = fmaf(zv.y, wr[11], a3);
                a0 = fmaf(zv.z, wr[16], a0); a1 = fmaf(zv.z, wr[17], a1);
                a2 = fmaf(zv.z, wr[18], a2); a3 = fmaf(zv.z, wr[19], a3);
                a0 = fmaf(zv.w, wr[24], a0); a1 = fmaf(zv.w, wr[25], a1);
                a2 = fmaf(zv.w, wr[26], a2); a3 = fmaf(zv.w, wr[27], a3);
            }
            plane[(jh+0)*784 + n] = a0;
            plane[(jh+1)*784 + n] = a1;
            plane[(jh+2)*784 + n] = a2;
            plane[(jh+3)*784 + n] = a3;
        }
    }
    __syncthreads();
    float* ob = out + ((size_t)b*256 + cg*8)*12544;
    for (int i4 = t; i4 < 3136; i4 += 256){
        int y = i4 / 28, xq = (i4 % 28) * 4;
        int y0 = ti0[y], y1 = min(y0+1, 27);
        float wy = twv[y];
        int x0q[4], x1q[4]; float wxq[4];
        #pragma unroll
        for (int qi = 0; qi < 4; ++qi){
            int xx = xq + qi;
            x0q[qi] = ti0[xx]; x1q[qi] = min(x0q[qi]+1, 27); wxq[qi] = twv[xx];
        }
        int base = y*112 + xq;
        #pragma unroll
        for (int j = 0; j < 8; ++j){
            const float* r0p = plane + j*784 + y0*28;
            const float* r1p = plane + j*784 + y1*28;
            float4 ov;
            #pragma unroll
            for (int qi = 0; qi < 4; ++qi){
                float a  = r0p[x0q[qi]] + (r1p[x0q[qi]] - r0p[x0q[qi]])*wy;
                float bb = r0p[x1q[qi]] + (r1p[x1q[qi]] - r0p[x1q[qi]])*wy;
                float v = a + (bb - a)*wxq[qi];
                if (qi == 0) ov.x = v; else if (qi == 1) ov.y = v;
                else if (qi == 2) ov.z = v; else ov.w = v;
            }
            *(float4*)(ob + (size_t)j*12544 + base) = ov;
        }
    }
}

extern "C" void kernel_launch(void* const* d_in, const int* in_sizes, int n_in,
                              void* d_out, int out_size, void* d_ws, size_t ws_size,
                              hipStream_t stream) {
    const float* x   = (const float*)d_in[0];
    const float* srw = (const float*)d_in[1];
    const float* srb = (const float*)d_in[2];
    const float* lng = (const float*)d_in[3];
    const float* lnb = (const float*)d_in[4];
    const float* qw  = (const float*)d_in[5];
    const float* k1w = (const float*)d_in[6];
    const float* v1w = (const float*)d_in[7];
    const float* k2w = (const float*)d_in[8];
    const float* v2w = (const float*)d_in[9];
    const float* pw  = (const float*)d_in[10];
    const float* pb  = (const float*)d_in[11];

    char*  Rws  = (char*)d_ws;
    float* pws  = (float*)(Rws + 12845056);
    char*  srwb = Rws + 25690112;
    char*  Wtm  = Rws + 26214400;
    char*  Wta  = Rws + 26279936;
    char*  QWt  = Rws + 26345472;
    float* z    = (float*)(Rws + 12845056);   // aliases pws (dead after k2)
    float* out  = (float*)d_out;

    ktw  <<<137,  256, 0, stream>>>(srw, qw, k1w, v1w, k2w, v2w, srwb, Wtm, Wta, QWt);
    k1   <<<1792, 256, 0, stream>>>(x, srwb, Rws, pws);
    k2   <<<448,  512, 0, stream>>>(pws, srb, lng, lnb, Wtm, Wta, QWt, Rws);
    kattn<<<896,  256, 0, stream>>>(Rws, z);
    kpu  <<<512,  256, 0, stream>>>(z, pw, pb, out);
}